// Round 14
// baseline (17595.233 us; speedup 1.0000x reference)
//
#include <hip/hip_runtime.h>
#include <hip/hip_bf16.h>
#include <math.h>

// ---- dims ----
#define Bn    128
#define NGn   2048
#define TTn   256
#define DOn   176
#define NBLK  256      // prep kernel blocks
#define NBLKM 64       // main kernel blocks
#define NTHR  1024
#define HPAR  65536          // 512*128 uints per parity, layout [k/8][128 b][8]
#define ACC_PAR 24576        // ints per parity in accI (8 pods x 16 b x 192)

typedef unsigned int uint;
typedef unsigned long long u64;
using f32x4 = __attribute__((ext_vector_type(4))) float;
using s16x8 = __attribute__((ext_vector_type(8))) short;
union FR { uint u[4]; s16x8 s; };

struct KA {
  const float *z,*Wz,*bz,*cU1,*cb1,*cW2,*cU2,*cb2,*Wcd,*bcd;
  const float *dW1,*dU1,*db1,*dW2,*dU2,*db2,*Wp,*bp;
  float *zT,*sT,*ggate,*h1cT,*ceT,*sdT,*beffP,*db1P,*db2P,*WEp,*out;
  uint *WAh,*WAl,*WBh,*WBl,*h1pk,*h2pk,*dh1pk,*dh2pk;
  int  *accI;
};

// ---- barrier state ----
__device__ unsigned g_cnt_l1[16 * 32];
__device__ unsigned g_cnt;
__device__ unsigned g_gen;
__device__ unsigned pod_slot[8 * 8 * 32];   // per-block monotonic flag, 128B apart

__device__ __forceinline__ float sigm(float x) { return 1.0f / (1.0f + __expf(-x)); }

__device__ __forceinline__ float aloadF(const float* p) {
  return __hip_atomic_load(p, __ATOMIC_RELAXED, __HIP_MEMORY_SCOPE_AGENT);
}
__device__ __forceinline__ void astoreF(float* p, float v) {
  __hip_atomic_store(p, v, __ATOMIC_RELAXED, __HIP_MEMORY_SCOPE_AGENT);
}
__device__ __forceinline__ uint aloadU(const uint* p) {
  return __hip_atomic_load(p, __ATOMIC_RELAXED, __HIP_MEMORY_SCOPE_AGENT);
}
__device__ __forceinline__ void astoreU(uint* p, uint v) {
  __hip_atomic_store(p, v, __ATOMIC_RELAXED, __HIP_MEMORY_SCOPE_AGENT);
}
__device__ __forceinline__ int aloadI(const int* p) {
  return __hip_atomic_load(p, __ATOMIC_RELAXED, __HIP_MEMORY_SCOPE_AGENT);
}
__device__ __forceinline__ u64 aload64(const u64* p) {
  return __hip_atomic_load(p, __ATOMIC_RELAXED, __HIP_MEMORY_SCOPE_AGENT);
}

// split v = hi + lo (both bf16, RNE)
__device__ __forceinline__ void split2(float v, unsigned short& h, unsigned short& l) {
  __hip_bfloat16 bh = __float2bfloat16(v);
  float hf = __bfloat162float(bh);
  __hip_bfloat16 bl = __float2bfloat16(v - hf);
  h = *(unsigned short*)&bh; l = *(unsigned short*)&bl;
}
__device__ __forceinline__ uint packsplit(float v) {
  unsigned short h, l; split2(v, h, l);
  return (uint)h | ((uint)l << 16);
}

// global barrier (prep kernel only; 256 blocks = 16 leaves x 16)
__device__ __forceinline__ void gbar() {
  __syncthreads();
  if (threadIdx.x == 0) {
    asm volatile("s_waitcnt vmcnt(0)" ::: "memory");
    unsigned g0 = __hip_atomic_load(&g_gen, __ATOMIC_RELAXED, __HIP_MEMORY_SCOPE_AGENT);
    unsigned p1 = __hip_atomic_fetch_add(&g_cnt_l1[(blockIdx.x >> 4) * 32], 1u,
                                         __ATOMIC_RELAXED, __HIP_MEMORY_SCOPE_AGENT);
    if (p1 == 15u) {
      unsigned p2 = __hip_atomic_fetch_add(&g_cnt, 1u, __ATOMIC_RELAXED, __HIP_MEMORY_SCOPE_AGENT);
      if (p2 == 15u) {
        #pragma unroll
        for (int i = 0; i < 16; i++)
          __hip_atomic_store(&g_cnt_l1[i * 32], 0u, __ATOMIC_RELAXED, __HIP_MEMORY_SCOPE_AGENT);
        __hip_atomic_store(&g_cnt, 0u, __ATOMIC_RELAXED, __HIP_MEMORY_SCOPE_AGENT);
        asm volatile("s_waitcnt vmcnt(0)" ::: "memory");
        __hip_atomic_fetch_add(&g_gen, 1u, __ATOMIC_RELAXED, __HIP_MEMORY_SCOPE_AGENT);
      }
    }
    while (__hip_atomic_load(&g_gen, __ATOMIC_RELAXED, __HIP_MEMORY_SCOPE_AGENT) == g0)
      __builtin_amdgcn_s_sleep(1);
  }
  __syncthreads();
}

// slot-flag pod barrier (8 blocks/pod): write own flag, lanes 0..7 poll all
__device__ __forceinline__ void pbarS(int pod, int j, unsigned& tgt) {
  __syncthreads();
  if (threadIdx.x < 8) {
    if (threadIdx.x == 0) {
      asm volatile("s_waitcnt vmcnt(0)" ::: "memory");   // data visible before flag
      astoreU(&pod_slot[(pod * 8 + j) * 32], tgt);
    }
    const uint* sl = &pod_slot[(pod * 8 + (int)threadIdx.x) * 32];
    while ((int)(aloadU(sl) - tgt) < 0) { }
  }
  __syncthreads();
  tgt += 1;
}

// ---------------- prep kernel f32 helpers (rounds 4-13 proven) ----------------
__device__ __forceinline__ void stageN(float* __restrict__ xs, const float* __restrict__ X,
                                       int nrows, int b0, int tid) {
  for (int i = tid; i < nrows * 16; i += NTHR)
    xs[i] = aloadF(X + (size_t)(i >> 4) * Bn + b0 + (i & 15));
}

template<int KC>
__device__ __forceinline__ void gemm16(const float* __restrict__ Wb, int colbase,
                                       int kq, int cg, int bg,
                                       const float* __restrict__ xsrc, float acc[16]) {
  const float* wp = Wb + (size_t)(kq * KC) * NGn + colbase + cg * 4;
  const float* xp = xsrc + (kq * KC) * 16 + bg * 4;
  #pragma unroll 2
  for (int kk = 0; kk < KC; kk++) {
    const float4 w4 = *(const float4*)(wp);
    const float4 x4 = *(const float4*)(xp);
    acc[0]  = fmaf(w4.x, x4.x, acc[0]);  acc[1]  = fmaf(w4.x, x4.y, acc[1]);
    acc[2]  = fmaf(w4.x, x4.z, acc[2]);  acc[3]  = fmaf(w4.x, x4.w, acc[3]);
    acc[4]  = fmaf(w4.y, x4.x, acc[4]);  acc[5]  = fmaf(w4.y, x4.y, acc[5]);
    acc[6]  = fmaf(w4.y, x4.z, acc[6]);  acc[7]  = fmaf(w4.y, x4.w, acc[7]);
    acc[8]  = fmaf(w4.z, x4.x, acc[8]);  acc[9]  = fmaf(w4.z, x4.y, acc[9]);
    acc[10] = fmaf(w4.z, x4.z, acc[10]); acc[11] = fmaf(w4.z, x4.w, acc[11]);
    acc[12] = fmaf(w4.w, x4.x, acc[12]); acc[13] = fmaf(w4.w, x4.y, acc[13]);
    acc[14] = fmaf(w4.w, x4.z, acc[14]); acc[15] = fmaf(w4.w, x4.w, acc[15]);
    wp += NGn; xp += 16;
  }
}

__device__ __forceinline__ void pstore(float* __restrict__ part, int kq, int cg, int bg,
                                       const float acc[16]) {
  #pragma unroll
  for (int c = 0; c < 4; c++) {
    float* p = part + (size_t)(kq * 64 + cg * 4 + c) * 17 + bg * 4;
    *(float4*)p = make_float4(acc[c*4], acc[c*4+1], acc[c*4+2], acc[c*4+3]);
  }
}

template<int MODE>
__device__ __forceinline__ void epi_plain(const float* bias, float* out,
                                          int colbase, int b0, int tid,
                                          const float* __restrict__ part) {
  int cl = tid >> 4, bl = tid & 15;
  float s = 0.0f;
  #pragma unroll
  for (int w = 0; w < 8; w++) s += part[(w * 64 + cl) * 17 + bl];
  if (bias) s += bias[colbase + cl];
  if (MODE == 0) s = tanhf(s);
  astoreF(out + (size_t)(colbase + cl) * Bn + b0 + bl, s);
}

__device__ __forceinline__ void cond_nl(const float* gb, const float* cbias,
                                        const float* cin, float* hout, int bid, int tid) {
  int i = bid * NTHR + tid;
  if (i < 512 * Bn) {
    int hid = i >> 7, b = i & 127;
    float gi = aloadF(gb + (size_t)hid * Bn + b)            + cbias[hid];
    float gf = aloadF(gb + (size_t)(512 + hid) * Bn + b)    + cbias[512 + hid];
    float gg = aloadF(gb + (size_t)(1024 + hid) * Bn + b)   + cbias[1024 + hid];
    float go = aloadF(gb + (size_t)(1536 + hid) * Bn + b)   + cbias[1536 + hid];
    float cprev = aloadF(cin + (size_t)hid * Bn + b);
    float c = sigm(gf) * cprev + sigm(gi) * tanhf(gg);
    astoreF(hout + (size_t)hid * Bn + b, sigm(go) * tanhf(c));
  }
}

// ---------------- prep kernel (256 blocks): preamble + weight packs ----------------
__global__ void __launch_bounds__(NTHR, 1)
hd_prep(KA A) {
  __shared__ float buf[25088];   // xs[16384] + part[8704]
  float* xs = buf;
  float* part = buf + 16384;
  const int bid = blockIdx.x, tid = threadIdx.x;
  const int lane = tid & 63;
  const int kqP = tid >> 6, cgP = lane & 15, bgP = lane >> 4;
  const int rP = bid & 31, btP = bid >> 5;
  const int htP = (rP & 7) * 4 + (rP >> 3);
  const int colbaseP = htP * 64, b0P = btP * 16;

  // ---- P-1: z transpose, bias perms, WEp, WA pack (256-col block layout), accI zero ----
  {
    const int i0 = bid * NTHR + tid;                 // 0..262143
    if (i0 < 512 * Bn) { int zb = i0 >> 9, zk = i0 & 511; astoreF(A.zT + (size_t)zk * Bn + zb, A.z[i0]); }
    if (i0 < NGn) {
      int hid = i0 >> 2, g = i0 & 3, sc = g * 512 + hid;
      astoreF(A.db1P + i0, A.db1[sc]);
      astoreF(A.db2P + i0, A.db2[sc]);
    }
    if (i0 < 2 * ACC_PAR) astoreU((uint*)(A.accI + i0), 0u);
    for (int i = i0; i < 512 * NGn; i += NBLK * NTHR) {   // WEp[k][cp]
      int k = i >> 11, pc = i & 2047;
      int hid = pc >> 2, g = pc & 3;
      astoreF(A.WEp + i, A.dW1[(size_t)(176 + k) * NGn + g * 512 + hid]);
    }
    for (int i = i0; i < 720896; i += NBLK * NTHR) {      // WA frag planes (8j x 22ks x 16nt)
      int col = i & 2047, kp = i >> 11, k = kp * 2;
      float w0, w1;
      if (k < 176)      { w0 = A.dW1[(size_t)k * NGn + col];       w1 = A.dW1[(size_t)(k + 1) * NGn + col]; }
      else if (k < 192) { w0 = 0.f; w1 = 0.f; }
      else              { w0 = A.dU1[(size_t)(k - 192) * NGn + col]; w1 = A.dU1[(size_t)(k - 191) * NGn + col]; }
      unsigned short h0, l0, h1, l1; split2(w0, h0, l0); split2(w1, h1, l1);
      int g = col >> 9, hid = col & 511;
      int jb = hid >> 6;                        // block 0..7 (64 hid each)
      int jcol = (hid & 63) * 4 + g;            // 0..255
      int nt = jcol >> 4, n = jcol & 15;
      int ks = k >> 5, kr = k & 31, lh = kr >> 3, q = (kr >> 1) & 3;
      int idx = ((jb * 22 + ks) * 16 + nt) * 256 + (lh * 16 + n) * 4 + q;
      astoreU(A.WAh + idx, (uint)h0 | ((uint)h1 << 16));
      astoreU(A.WAl + idx, (uint)l0 | ((uint)l1 << 16));
    }
  }
  gbar();
  // ---- pre0: sT = tanh(z @ Wz + bz) ----
  {
    stageN(xs, A.zT, 512, b0P, tid); __syncthreads();
    if (tid < 512) {
      float acc[16] = {0,0,0,0,0,0,0,0,0,0,0,0,0,0,0,0};
      gemm16<64>(A.Wz, colbaseP, kqP, cgP, bgP, xs, acc);
      pstore(part, kqP, cgP, bgP, acc);
    }
    __syncthreads();
    epi_plain<0>(A.bz, A.sT, colbaseP, b0P, tid, part);
  }
  gbar();
  // ---- pre1: conductor L1 gates ----
  {
    stageN(xs, A.sT, 512, b0P, tid); __syncthreads();
    if (tid < 512) {
      float acc[16] = {0,0,0,0,0,0,0,0,0,0,0,0,0,0,0,0};
      gemm16<64>(A.cU1, colbaseP, kqP, cgP, bgP, xs, acc);
      pstore(part, kqP, cgP, bgP, acc);
    }
    __syncthreads();
    epi_plain<1>(nullptr, A.ggate, colbaseP, b0P, tid, part);
  }
  gbar();
  cond_nl(A.ggate, A.cb1, A.sT + (size_t)512 * Bn, A.h1cT, bid, tid);
  gbar();
  // ---- pre2: conductor L2 gates ----
  {
    stageN(xs, A.h1cT, 512, b0P, tid);
    stageN(xs + 8192, A.sT + (size_t)1024 * Bn, 512, b0P, tid);
    __syncthreads();
    if (tid < 512) {
      float acc[16] = {0,0,0,0,0,0,0,0,0,0,0,0,0,0,0,0};
      gemm16<64>(A.cW2, colbaseP, kqP, cgP, bgP, xs, acc);
      gemm16<64>(A.cU2, colbaseP, kqP, cgP, bgP, xs + 8192, acc);
      pstore(part, kqP, cgP, bgP, acc);
    }
    __syncthreads();
    epi_plain<1>(nullptr, A.ggate, colbaseP, b0P, tid, part);
  }
  gbar();
  cond_nl(A.ggate, A.cb2, A.sT + (size_t)1536 * Bn, A.ceT, bid, tid);
  gbar();
  // ---- pre3: sdT = tanh(ce @ Wcd + bcd); beffP = db1P + ce @ WEp ----
  {
    stageN(xs, A.ceT, 512, b0P, tid); __syncthreads();
    if (tid < 512) {
      float acc[16] = {0,0,0,0,0,0,0,0,0,0,0,0,0,0,0,0};
      gemm16<64>(A.Wcd, colbaseP, kqP, cgP, bgP, xs, acc);
      pstore(part, kqP, cgP, bgP, acc);
    }
    __syncthreads();
    epi_plain<0>(A.bcd, A.sdT, colbaseP, b0P, tid, part);
    __syncthreads();
    if (tid < 512) {
      float acc[16] = {0,0,0,0,0,0,0,0,0,0,0,0,0,0,0,0};
      gemm16<64>(A.WEp, colbaseP, kqP, cgP, bgP, xs, acc);
      pstore(part, kqP, cgP, bgP, acc);
    }
    __syncthreads();
    epi_plain<1>(A.db1P, A.beffP, colbaseP, b0P, tid, part);
  }
  gbar();
  // ---- P4: WB pack (overwrites WEp; 8j x 32ks x 16nt) + dh packs ([kt][b][8]) ----
  {
    const int i0 = bid * NTHR + tid;
    for (int i = i0; i < 1048576; i += NBLK * NTHR) {
      int col = i & 2047, kp = i >> 11, k = kp * 2;
      float w0, w1;
      if (k < 512) { w0 = A.dW2[(size_t)k * NGn + col];         w1 = A.dW2[(size_t)(k + 1) * NGn + col]; }
      else         { w0 = A.dU2[(size_t)(k - 512) * NGn + col]; w1 = A.dU2[(size_t)(k - 511) * NGn + col]; }
      unsigned short h0, l0, h1, l1; split2(w0, h0, l0); split2(w1, h1, l1);
      int g = col >> 9, hid = col & 511;
      int jb = hid >> 6;
      int jcol = (hid & 63) * 4 + g;
      int nt = jcol >> 4, n = jcol & 15;
      int ks = k >> 5, kr = k & 31, lh = kr >> 3, q = (kr >> 1) & 3;
      int idx = ((jb * 32 + ks) * 16 + nt) * 256 + (lh * 16 + n) * 4 + q;
      astoreU(A.WBh + idx, (uint)h0 | ((uint)h1 << 16));
      astoreU(A.WBl + idx, (uint)l0 | ((uint)l1 << 16));
    }
    if (i0 < 512 * Bn) {
      int hid = i0 >> 7, b = i0 & 127;
      astoreU(A.dh1pk + ((size_t)((hid >> 3) * 128 + b)) * 8 + (hid & 7),
              packsplit(aloadF(A.sdT + (size_t)hid * Bn + b)));
      astoreU(A.dh2pk + ((size_t)((hid >> 3) * 128 + b)) * 8 + (hid & 7),
              packsplit(aloadF(A.sdT + (size_t)(1024 + hid) * Bn + b)));
    }
  }
  // kernel end = device-wide completion before hd_main starts (stream order)
}

// ---------------- main kernel (64 blocks): 8 pods x 8 blocks x 256 cols ----------------
// frag maps (rounds 5-13 verified): A(x): m=lane&15, k=(lane>>4)*8+e.
// B(w): n=lane&15, k=(lane>>4)*8+e. D: n=lane&15, m=(lane>>4)*4+reg.
__device__ __forceinline__ void unpackL17(const uint* __restrict__ p, FR& xh, FR& xl) {
  uint w[8];
  #pragma unroll
  for (int e = 0; e < 8; e++) w[e] = p[e * 17];
  xh.u[0] = (w[0] & 0xffffu) | (w[1] << 16); xl.u[0] = (w[0] >> 16) | (w[1] & 0xffff0000u);
  xh.u[1] = (w[2] & 0xffffu) | (w[3] << 16); xl.u[1] = (w[2] >> 16) | (w[3] & 0xffff0000u);
  xh.u[2] = (w[4] & 0xffffu) | (w[5] << 16); xl.u[2] = (w[4] >> 16) | (w[5] & 0xffff0000u);
  xh.u[3] = (w[6] & 0xffffu) | (w[7] << 16); xl.u[3] = (w[6] >> 16) | (w[7] & 0xffff0000u);
}

#define MFMA3(ACC, XH, XL, WH, WL)                                            \
  ACC = __builtin_amdgcn_mfma_f32_16x16x32_bf16(XH.s, WH.s, ACC, 0, 0, 0);    \
  ACC = __builtin_amdgcn_mfma_f32_16x16x32_bf16(XL.s, WH.s, ACC, 0, 0, 0);    \
  ACC = __builtin_amdgcn_mfma_f32_16x16x32_bf16(XH.s, WL.s, ACC, 0, 0, 0);

// stage 512 k-rows x 16 batch from packed global [kt][128][8] into SB rows [r0..r0+512)
// 1024 threads: thread = (kt 0..63, bl 0..15); 32B contiguous per thread.
__device__ __forceinline__ void stage512(uint* __restrict__ SB, int r0,
                                         const uint* __restrict__ src, int b0, int tid) {
  const int kt = tid >> 4, bl = tid & 15;
  const u64* p = (const u64*)src + ((size_t)(kt * 128 + b0 + bl)) * 4;
  u64 d0 = aload64(p), d1 = aload64(p + 1), d2 = aload64(p + 2), d3 = aload64(p + 3);
  uint* q = SB + (r0 + kt * 8) * 17 + bl;
  q[0 * 17] = (uint)d0; q[1 * 17] = (uint)(d0 >> 32);
  q[2 * 17] = (uint)d1; q[3 * 17] = (uint)(d1 >> 32);
  q[4 * 17] = (uint)d2; q[5 * 17] = (uint)(d2 >> 32);
  q[6 * 17] = (uint)d3; q[7 * 17] = (uint)(d3 >> 32);
}

__global__ void __launch_bounds__(NTHR, 1)
hd_main(KA A) {
  __shared__ float buf[32512];   // 127 KB
  uint*  SB  = (uint*)buf;           // 1024 rows x 17 = 17408
  uint*  NT  = (uint*)(buf + 17408); // 192 rows x 17 = 3264
  float* gb  = buf + 20672;          // 256 cols x 17 = 4352
  float* cst = buf + 25024;          // c1[1024] | c2[1024]
  float* h2s = buf + 27072;          // 64 x 17 = 1088
  float* beffL = buf + 28160;        // 4096
  float* db2L  = buf + 32256;        // 256

  const int bid = blockIdx.x, tid = threadIdx.x;
  const int wid = tid >> 6, lane = tid & 63;
  const int m = lane & 15, kh = lane >> 4;   // A-frag batch / k-half
  const int j = bid & 7, pod = bid >> 3;
  const int b0 = pod * 16;
  const int nt = wid;                        // wave owns one 16-col tile

  unsigned tgt = aloadU(&pod_slot[(pod * 8 + j) * 32]) + 1;

  // ---- block init ----
  #pragma unroll
  for (int r = 0; r < 4; r++) {
    int idx = tid + r * NTHR;                // 0..4095
    int cl = idx >> 4, bl = idx & 15;
    beffL[idx] = aloadF(A.beffP + (size_t)(j * 256 + cl) * Bn + b0 + bl);
  }
  if (tid < 256) db2L[tid] = A.db2P[j * 256 + tid];
  #pragma unroll
  for (int r = 0; r < 4; r++) {
    int idx = tid + r * NTHR;
    if (idx < 3264) NT[idx] = 0u;            // note(0) = 0 (+pad)
  }
  __syncthreads();

  int* accI = A.accI + pod * 3072;

  for (int t = 0; t <= TTn; t++) {
    const int par = t & 1;
    const bool rst = (t & 15) == 0;
    const bool last = (t == TTn);

    // ==== softmax front: accI(par^1) -> NT + out(t-1); wave = batch ====
    if (t > 0) {
      const int* ai = accI + ((par ^ 1) * ACC_PAR) + wid * 192 + lane;
      int a0 = aloadI(ai), a1 = aloadI(ai + 64), a2 = aloadI(ai + 128);
      float lg[3], pv[3];
      lg[0] = (lane < DOn)       ? (float)a0 * (1.0f/1048576.0f) + A.bp[lane]       : -1e30f;
      lg[1] = (lane+64 < DOn)    ? (float)a1 * (1.0f/1048576.0f) + A.bp[lane+64]    : -1e30f;
      lg[2] = (lane+128 < DOn)   ? (float)a2 * (1.0f/1048576.0f) + A.bp[lane+128]   : -1e30f;
      float mx = fmaxf(fmaxf(lg[0], lg[1]), lg[2]);
      #pragma unroll
      for (int d = 1; d < 64; d <<= 1) mx = fmaxf(mx, __shfl_xor(mx, d));
      float sum = 0.f;
      #pragma unroll
      for (int rep = 0; rep < 3; rep++) {
        int o = lane + rep * 64;
        pv[rep] = (o < DOn) ? __expf(lg[rep] - mx) : 0.f;
        sum += pv[rep];
      }
      #pragma unroll
      for (int d = 1; d < 64; d <<= 1) sum += __shfl_xor(sum, d);
      const float inv = 1.0f / sum;
      #pragma unroll
      for (int rep = 0; rep < 3; rep++) {
        int o = lane + rep * 64;
        if (o < 192) {
          float p = pv[rep] * inv;
          NT[o * 17 + wid] = (o < DOn) ? packsplit(p) : 0u;
          if ((wid & 7) == j && o < DOn)
            A.out[((size_t)(b0 + wid) * TTn + (t - 1)) * DOn + o] = p;
        }
      }
    }
    if (last) break;

    // ==== stage h2(t-1)/dh2 -> SB[512..1023]; at rst also dh1 -> SB[0..511] ====
    stage512(SB, 512, rst ? A.dh2pk : (A.h2pk + (par ^ 1) * HPAR), b0, tid);
    if (rst) stage512(SB, 0, A.dh1pk, b0, tid);
    __syncthreads();

    // ==== decoder L1: wave nt owns full K (22 ks), 2 interleaved accumulators ====
    {
      const uint* WH = A.WAh + (size_t)j * 90112;   // 22*16*256
      const uint* WL = A.WAl + (size_t)j * 90112;
      f32x4 a0 = {0,0,0,0}, a1 = {0,0,0,0};
      for (int ks = 0; ks < 22; ks += 2) {
        FR xh, xl, wh, wl;
        const uint* xp0 = (ks < 6) ? (NT + (ks * 32 + kh * 8) * 17 + m)
                                   : (SB + ((ks - 6) * 32 + kh * 8) * 17 + m);
        unpackL17(xp0, xh, xl);
        *(uint4*)wh.u = *(const uint4*)(WH + (ks * 16 + nt) * 256 + lane * 4);
        *(uint4*)wl.u = *(const uint4*)(WL + (ks * 16 + nt) * 256 + lane * 4);
        MFMA3(a0, xh, xl, wh, wl)
        const int k2 = ks + 1;
        const uint* xp1 = (k2 < 6) ? (NT + (k2 * 32 + kh * 8) * 17 + m)
                                   : (SB + ((k2 - 6) * 32 + kh * 8) * 17 + m);
        unpackL17(xp1, xh, xl);
        *(uint4*)wh.u = *(const uint4*)(WH + (k2 * 16 + nt) * 256 + lane * 4);
        *(uint4*)wl.u = *(const uint4*)(WL + (k2 * 16 + nt) * 256 + lane * 4);
        MFMA3(a1, xh, xl, wh, wl)
      }
      #pragma unroll
      for (int r = 0; r < 4; r++)
        gb[(nt * 16 + (lane & 15)) * 17 + kh * 4 + r] = a0[r] + a1[r];
    }
    __syncthreads();
    // epilogue L1 (all 1024 threads): thread = (hid_local, batch)
    {
      const int hl = tid >> 4, bl = tid & 15;
      float g4[4];
      #pragma unroll
      for (int g = 0; g < 4; g++)
        g4[g] = gb[(hl * 4 + g) * 17 + bl] + beffL[(hl * 4 + g) * 16 + bl];
      const int hid = j * 64 + hl;
      float cp = rst ? aloadF(A.sdT + (size_t)(512 + hid) * Bn + b0 + bl) : cst[tid];
      float cc = sigm(g4[1]) * cp + sigm(g4[0]) * tanhf(g4[2]);
      cst[tid] = cc;
      astoreU(A.h1pk + par * HPAR + ((size_t)((hid >> 3) * 128 + b0 + bl)) * 8 + (hid & 7),
              packsplit(sigm(g4[3]) * tanhf(cc)));
    }
    pbarS(pod, j, tgt);

    // ==== stage h1(t) -> SB[0..511] ====
    stage512(SB, 0, A.h1pk + par * HPAR, b0, tid);
    __syncthreads();

    // ==== decoder L2: 32 ks (h1 rows 0..511, h2 rows 512..1023) ====
    {
      const uint* WH = A.WBh + (size_t)j * 131072;  // 32*16*256
      const uint* WL = A.WBl + (size_t)j * 131072;
      f32x4 a0 = {0,0,0,0}, a1 = {0,0,0,0};
      for (int ks = 0; ks < 32; ks += 2) {
        FR xh, xl, wh, wl;
        unpackL17(SB + (ks * 32 + kh * 8) * 17 + m, xh, xl);
        *(uint4*)wh.u = *(const uint4*)(WH + (ks * 16 + nt) * 256 + lane * 4);
        *(uint4*)wl.u = *(const uint4*)(WL + (ks * 16 + nt) * 256 + lane * 4);
        MFMA3(a0, xh, xl, wh, wl)
        unpackL17(SB + ((ks + 1) * 32 + kh * 8) * 17 + m, xh, xl);
        *(uint4*)wh.u = *(const uint4*)(WH + ((ks + 1) * 16 + nt) * 256 + lane * 4);
        *(uint4*)wl.u = *(const uint4*)(WL + ((ks + 1) * 16 + nt) * 256 + lane * 4);
        MFMA3(a1, xh, xl, wh, wl)
      }
      #pragma unroll
      for (int r = 0; r < 4; r++)
        gb[(nt * 16 + (lane & 15)) * 17 + kh * 4 + r] = a0[r] + a1[r];
    }
    __syncthreads();
    // epilogue L2
    {
      const int hl = tid >> 4, bl = tid & 15;
      float g4[4];
      #pragma unroll
      for (int g = 0; g < 4; g++)
        g4[g] = gb[(hl * 4 + g) * 17 + bl] + db2L[hl * 4 + g];
      const int hid = j * 64 + hl;
      float cp = rst ? aloadF(A.sdT + (size_t)(1536 + hid) * Bn + b0 + bl) : cst[1024 + tid];
      float cc = sigm(g4[1]) * cp + sigm(g4[0]) * tanhf(g4[2]);
      cst[1024 + tid] = cc;
      float h2v = sigm(g4[3]) * tanhf(cc);
      h2s[hl * 17 + bl] = h2v;
      astoreU(A.h2pk + par * HPAR + ((size_t)((hid >> 3) * 128 + b0 + bl)) * 8 + (hid & 7),
              packsplit(h2v));
    }
    __syncthreads();
    // partial projection logits over this block's 64-hid slice -> fixed-point atomics
    {
      const int o = tid & 255, q = tid >> 8;   // q = 4 batch groups of 4
      if (o < DOn) {
        float s0 = 0.f, s1 = 0.f, s2 = 0.f, s3 = 0.f;
        for (int h = 0; h < 64; h++) {
          const float w = A.Wp[(size_t)(j * 64 + h) * DOn + o];
          s0 = fmaf(h2s[h * 17 + q * 4 + 0], w, s0);
          s1 = fmaf(h2s[h * 17 + q * 4 + 1], w, s1);
          s2 = fmaf(h2s[h * 17 + q * 4 + 2], w, s2);
          s3 = fmaf(h2s[h * 17 + q * 4 + 3], w, s3);
        }
        __hip_atomic_fetch_add(accI + par * ACC_PAR + (q * 4 + 0) * 192 + o,
                               __float2int_rn(s0 * 1048576.0f), __ATOMIC_RELAXED, __HIP_MEMORY_SCOPE_AGENT);
        __hip_atomic_fetch_add(accI + par * ACC_PAR + (q * 4 + 1) * 192 + o,
                               __float2int_rn(s1 * 1048576.0f), __ATOMIC_RELAXED, __HIP_MEMORY_SCOPE_AGENT);
        __hip_atomic_fetch_add(accI + par * ACC_PAR + (q * 4 + 2) * 192 + o,
                               __float2int_rn(s2 * 1048576.0f), __ATOMIC_RELAXED, __HIP_MEMORY_SCOPE_AGENT);
        __hip_atomic_fetch_add(accI + par * ACC_PAR + (q * 4 + 3) * 192 + o,
                               __float2int_rn(s3 * 1048576.0f), __ATOMIC_RELAXED, __HIP_MEMORY_SCOPE_AGENT);
      }
      if (tid < 384)
        astoreU((uint*)(accI + (par ^ 1) * ACC_PAR + j * 384 + tid), 0u);
    }
    pbarS(pod, j, tgt);
  }
}

extern "C" void kernel_launch(void* const* d_in, const int* in_sizes, int n_in,
                              void* d_out, int out_size, void* d_ws, size_t ws_size,
                              hipStream_t stream) {
  (void)in_sizes; (void)n_in; (void)out_size; (void)ws_size;
  KA a;
  a.z   = (const float*)d_in[0];
  a.Wz  = (const float*)d_in[3];  a.bz  = (const float*)d_in[4];
  // d_in[5] = cond_W1 unused (conductor input x0 == 0)
  a.cU1 = (const float*)d_in[6];  a.cb1 = (const float*)d_in[7];
  a.cW2 = (const float*)d_in[8];  a.cU2 = (const float*)d_in[9];  a.cb2 = (const float*)d_in[10];
  a.Wcd = (const float*)d_in[11]; a.bcd = (const float*)d_in[12];
  a.dW1 = (const float*)d_in[13]; a.dU1 = (const float*)d_in[14]; a.db1 = (const float*)d_in[15];
  a.dW2 = (const float*)d_in[16]; a.dU2 = (const float*)d_in[17]; a.db2 = (const float*)d_in[18];
  a.Wp  = (const float*)d_in[19]; a.bp  = (const float*)d_in[20];

  float* ws = (float*)d_ws;
  size_t off = 0;
  a.zT    = ws + off; off += (size_t)512  * Bn;
  a.sT    = ws + off; off += (size_t)NGn  * Bn;
  a.ggate = ws + off; off += (size_t)NGn  * Bn;
  a.h1cT  = ws + off; off += (size_t)512  * Bn;
  a.ceT   = ws + off; off += (size_t)512  * Bn;
  a.sdT   = ws + off; off += (size_t)NGn  * Bn;       // dh1|dc1|dh2|dc2
  a.beffP = ws + off; off += (size_t)NGn  * Bn;       // [cp][b]
  a.db1P  = ws + off; off += (size_t)NGn;
  a.db2P  = ws + off; off += (size_t)NGn;
  a.WEp   = ws + off; off += (size_t)512 * NGn;       // aliased by WBh in P4
  a.WBh   = (uint*)a.WEp;
  a.WBl   = (uint*)(ws + off); off += (size_t)1048576;
  a.WAh   = (uint*)(ws + off); off += (size_t)720896;
  a.WAl   = (uint*)(ws + off); off += (size_t)720896;
  a.h1pk  = (uint*)(ws + off); off += (size_t)2 * HPAR;
  a.h2pk  = (uint*)(ws + off); off += (size_t)2 * HPAR;
  a.dh1pk = (uint*)(ws + off); off += (size_t)HPAR;
  a.dh2pk = (uint*)(ws + off); off += (size_t)HPAR;
  a.accI  = (int*)(ws + off);  off += (size_t)2 * ACC_PAR;
  a.out   = (float*)d_out;

  hd_prep<<<dim3(NBLK),  dim3(NTHR), 0, stream>>>(a);
  hd_main<<<dim3(NBLKM), dim3(NTHR), 0, stream>>>(a);
}

// Round 15
// 12566.668 us; speedup vs baseline: 1.4002x; 1.4002x over previous
//
#include <hip/hip_runtime.h>
#include <hip/hip_bf16.h>
#include <math.h>

// ---- dims ----
#define Bn    128
#define NGn   2048
#define TTn   256
#define DOn   176
#define NBLK  256      // prep + main blocks
#define NTHR  1024
#define HPAR  65536          // 512*128 uints per parity, layout [k/8][128 b][8]
#define ACC_PAR 24576        // ints per parity in accI (16 pods x 8 b x 192)

typedef unsigned int uint;
typedef unsigned long long u64;
using f32x4 = __attribute__((ext_vector_type(4))) float;
using s16x8 = __attribute__((ext_vector_type(8))) short;
union FR { uint u[4]; s16x8 s; };

struct KA {
  const float *z,*Wz,*bz,*cU1,*cb1,*cW2,*cU2,*cb2,*Wcd,*bcd;
  const float *dW1,*dU1,*db1,*dW2,*dU2,*db2,*Wp,*bp;
  float *zT,*sT,*ggate,*h1cT,*ceT,*sdT,*beffP,*db1P,*db2P,*WEp,*out;
  uint *WAh,*WAl,*WBh,*WBl,*h1pk,*h2pk,*dh1pk,*dh2pk;
  int  *accI;
};

// ---- barrier state ----
__device__ unsigned g_cnt_l1[16 * 32];
__device__ unsigned g_cnt;
__device__ unsigned g_gen;
__device__ unsigned pod_slot[16 * 16 * 32];   // per-block monotonic flag, 128B apart

__device__ __forceinline__ float sigm(float x) { return 1.0f / (1.0f + __expf(-x)); }

__device__ __forceinline__ float aloadF(const float* p) {
  return __hip_atomic_load(p, __ATOMIC_RELAXED, __HIP_MEMORY_SCOPE_AGENT);
}
__device__ __forceinline__ void astoreF(float* p, float v) {
  __hip_atomic_store(p, v, __ATOMIC_RELAXED, __HIP_MEMORY_SCOPE_AGENT);
}
__device__ __forceinline__ uint aloadU(const uint* p) {
  return __hip_atomic_load(p, __ATOMIC_RELAXED, __HIP_MEMORY_SCOPE_AGENT);
}
__device__ __forceinline__ void astoreU(uint* p, uint v) {
  __hip_atomic_store(p, v, __ATOMIC_RELAXED, __HIP_MEMORY_SCOPE_AGENT);
}
__device__ __forceinline__ int aloadI(const int* p) {
  return __hip_atomic_load(p, __ATOMIC_RELAXED, __HIP_MEMORY_SCOPE_AGENT);
}
__device__ __forceinline__ u64 aload64(const u64* p) {
  return __hip_atomic_load(p, __ATOMIC_RELAXED, __HIP_MEMORY_SCOPE_AGENT);
}

// split v = hi + lo (both bf16, RNE)
__device__ __forceinline__ void split2(float v, unsigned short& h, unsigned short& l) {
  __hip_bfloat16 bh = __float2bfloat16(v);
  float hf = __bfloat162float(bh);
  __hip_bfloat16 bl = __float2bfloat16(v - hf);
  h = *(unsigned short*)&bh; l = *(unsigned short*)&bl;
}
__device__ __forceinline__ uint packsplit(float v) {
  unsigned short h, l; split2(v, h, l);
  return (uint)h | ((uint)l << 16);
}

// global barrier (prep kernel only)
__device__ __forceinline__ void gbar() {
  __syncthreads();
  if (threadIdx.x == 0) {
    asm volatile("s_waitcnt vmcnt(0)" ::: "memory");
    unsigned g0 = __hip_atomic_load(&g_gen, __ATOMIC_RELAXED, __HIP_MEMORY_SCOPE_AGENT);
    unsigned p1 = __hip_atomic_fetch_add(&g_cnt_l1[(blockIdx.x >> 4) * 32], 1u,
                                         __ATOMIC_RELAXED, __HIP_MEMORY_SCOPE_AGENT);
    if (p1 == 15u) {
      unsigned p2 = __hip_atomic_fetch_add(&g_cnt, 1u, __ATOMIC_RELAXED, __HIP_MEMORY_SCOPE_AGENT);
      if (p2 == 15u) {
        #pragma unroll
        for (int i = 0; i < 16; i++)
          __hip_atomic_store(&g_cnt_l1[i * 32], 0u, __ATOMIC_RELAXED, __HIP_MEMORY_SCOPE_AGENT);
        __hip_atomic_store(&g_cnt, 0u, __ATOMIC_RELAXED, __HIP_MEMORY_SCOPE_AGENT);
        asm volatile("s_waitcnt vmcnt(0)" ::: "memory");
        __hip_atomic_fetch_add(&g_gen, 1u, __ATOMIC_RELAXED, __HIP_MEMORY_SCOPE_AGENT);
      }
    }
    while (__hip_atomic_load(&g_gen, __ATOMIC_RELAXED, __HIP_MEMORY_SCOPE_AGENT) == g0)
      __builtin_amdgcn_s_sleep(1);
  }
  __syncthreads();
}

// slot-flag pod barrier (16 blocks/pod): write own flag, lanes 0..15 poll all
__device__ __forceinline__ void pbarS(int pod, int j, unsigned& tgt) {
  __syncthreads();
  if (threadIdx.x < 16) {
    if (threadIdx.x == 0) {
      asm volatile("s_waitcnt vmcnt(0)" ::: "memory");   // data visible before flag
      astoreU(&pod_slot[(pod * 16 + j) * 32], tgt);
    }
    const uint* sl = &pod_slot[(pod * 16 + (int)threadIdx.x) * 32];
    while ((int)(aloadU(sl) - tgt) < 0) { }
  }
  __syncthreads();
  tgt += 1;
}

// ---------------- prep kernel f32 helpers (rounds 4-13 proven) ----------------
__device__ __forceinline__ void stageN(float* __restrict__ xs, const float* __restrict__ X,
                                       int nrows, int b0, int tid) {
  for (int i = tid; i < nrows * 16; i += NTHR)
    xs[i] = aloadF(X + (size_t)(i >> 4) * Bn + b0 + (i & 15));
}

template<int KC>
__device__ __forceinline__ void gemm16(const float* __restrict__ Wb, int colbase,
                                       int kq, int cg, int bg,
                                       const float* __restrict__ xsrc, float acc[16]) {
  const float* wp = Wb + (size_t)(kq * KC) * NGn + colbase + cg * 4;
  const float* xp = xsrc + (kq * KC) * 16 + bg * 4;
  #pragma unroll 2
  for (int kk = 0; kk < KC; kk++) {
    const float4 w4 = *(const float4*)(wp);
    const float4 x4 = *(const float4*)(xp);
    acc[0]  = fmaf(w4.x, x4.x, acc[0]);  acc[1]  = fmaf(w4.x, x4.y, acc[1]);
    acc[2]  = fmaf(w4.x, x4.z, acc[2]);  acc[3]  = fmaf(w4.x, x4.w, acc[3]);
    acc[4]  = fmaf(w4.y, x4.x, acc[4]);  acc[5]  = fmaf(w4.y, x4.y, acc[5]);
    acc[6]  = fmaf(w4.y, x4.z, acc[6]);  acc[7]  = fmaf(w4.y, x4.w, acc[7]);
    acc[8]  = fmaf(w4.z, x4.x, acc[8]);  acc[9]  = fmaf(w4.z, x4.y, acc[9]);
    acc[10] = fmaf(w4.z, x4.z, acc[10]); acc[11] = fmaf(w4.z, x4.w, acc[11]);
    acc[12] = fmaf(w4.w, x4.x, acc[12]); acc[13] = fmaf(w4.w, x4.y, acc[13]);
    acc[14] = fmaf(w4.w, x4.z, acc[14]); acc[15] = fmaf(w4.w, x4.w, acc[15]);
    wp += NGn; xp += 16;
  }
}

__device__ __forceinline__ void pstore(float* __restrict__ part, int kq, int cg, int bg,
                                       const float acc[16]) {
  #pragma unroll
  for (int c = 0; c < 4; c++) {
    float* p = part + (size_t)(kq * 64 + cg * 4 + c) * 17 + bg * 4;
    *(float4*)p = make_float4(acc[c*4], acc[c*4+1], acc[c*4+2], acc[c*4+3]);
  }
}

template<int MODE>
__device__ __forceinline__ void epi_plain(const float* bias, float* out,
                                          int colbase, int b0, int tid,
                                          const float* __restrict__ part) {
  int cl = tid >> 4, bl = tid & 15;
  float s = 0.0f;
  #pragma unroll
  for (int w = 0; w < 8; w++) s += part[(w * 64 + cl) * 17 + bl];
  if (bias) s += bias[colbase + cl];
  if (MODE == 0) s = tanhf(s);
  astoreF(out + (size_t)(colbase + cl) * Bn + b0 + bl, s);
}

__device__ __forceinline__ void cond_nl(const float* gb, const float* cbias,
                                        const float* cin, float* hout, int bid, int tid) {
  int i = bid * NTHR + tid;
  if (i < 512 * Bn) {
    int hid = i >> 7, b = i & 127;
    float gi = aloadF(gb + (size_t)hid * Bn + b)            + cbias[hid];
    float gf = aloadF(gb + (size_t)(512 + hid) * Bn + b)    + cbias[512 + hid];
    float gg = aloadF(gb + (size_t)(1024 + hid) * Bn + b)   + cbias[1024 + hid];
    float go = aloadF(gb + (size_t)(1536 + hid) * Bn + b)   + cbias[1536 + hid];
    float cprev = aloadF(cin + (size_t)hid * Bn + b);
    float c = sigm(gf) * cprev + sigm(gi) * tanhf(gg);
    astoreF(hout + (size_t)hid * Bn + b, sigm(go) * tanhf(c));
  }
}

// ---------------- prep kernel (256 blocks) ----------------
__global__ void __launch_bounds__(NTHR, 1)
hd_prep(KA A) {
  __shared__ float buf[25088];   // xs[16384] + part[8704]
  float* xs = buf;
  float* part = buf + 16384;
  const int bid = blockIdx.x, tid = threadIdx.x;
  const int lane = tid & 63;
  const int kqP = tid >> 6, cgP = lane & 15, bgP = lane >> 4;
  const int rP = bid & 31, btP = bid >> 5;
  const int htP = (rP & 7) * 4 + (rP >> 3);
  const int colbaseP = htP * 64, b0P = btP * 16;

  // ---- P-1: z transpose, bias perms, WEp, WA pack (16-block layout), accI zero ----
  {
    const int i0 = bid * NTHR + tid;
    if (i0 < 512 * Bn) { int zb = i0 >> 9, zk = i0 & 511; astoreF(A.zT + (size_t)zk * Bn + zb, A.z[i0]); }
    if (i0 < NGn) {
      int hid = i0 >> 2, g = i0 & 3, sc = g * 512 + hid;
      astoreF(A.db1P + i0, A.db1[sc]);
      astoreF(A.db2P + i0, A.db2[sc]);
    }
    if (i0 < 2 * ACC_PAR) astoreU((uint*)(A.accI + i0), 0u);
    for (int i = i0; i < 512 * NGn; i += NBLK * NTHR) {   // WEp[k][cp]
      int k = i >> 11, pc = i & 2047;
      int hid = pc >> 2, g = pc & 3;
      astoreF(A.WEp + i, A.dW1[(size_t)(176 + k) * NGn + g * 512 + hid]);
    }
    for (int i = i0; i < 720896; i += NBLK * NTHR) {      // WA frag planes (16j x 22ks x 8nt)
      int col = i & 2047, kp = i >> 11, k = kp * 2;
      float w0, w1;
      if (k < 176)      { w0 = A.dW1[(size_t)k * NGn + col];       w1 = A.dW1[(size_t)(k + 1) * NGn + col]; }
      else if (k < 192) { w0 = 0.f; w1 = 0.f; }
      else              { w0 = A.dU1[(size_t)(k - 192) * NGn + col]; w1 = A.dU1[(size_t)(k - 191) * NGn + col]; }
      unsigned short h0, l0, h1, l1; split2(w0, h0, l0); split2(w1, h1, l1);
      int g = col >> 9, hid = col & 511;
      int jb = hid >> 5;                        // block 0..15 (32 hid each)
      int jcol = (hid & 31) * 4 + g;            // 0..127
      int nt = jcol >> 4, n = jcol & 15;
      int ks = k >> 5, kr = k & 31, lh = kr >> 3, q = (kr >> 1) & 3;
      int idx = ((jb * 22 + ks) * 8 + nt) * 256 + (lh * 16 + n) * 4 + q;
      astoreU(A.WAh + idx, (uint)h0 | ((uint)h1 << 16));
      astoreU(A.WAl + idx, (uint)l0 | ((uint)l1 << 16));
    }
  }
  gbar();
  // ---- pre0: sT = tanh(z @ Wz + bz) ----
  {
    stageN(xs, A.zT, 512, b0P, tid); __syncthreads();
    if (tid < 512) {
      float acc[16] = {0,0,0,0,0,0,0,0,0,0,0,0,0,0,0,0};
      gemm16<64>(A.Wz, colbaseP, kqP, cgP, bgP, xs, acc);
      pstore(part, kqP, cgP, bgP, acc);
    }
    __syncthreads();
    epi_plain<0>(A.bz, A.sT, colbaseP, b0P, tid, part);
  }
  gbar();
  // ---- pre1: conductor L1 gates ----
  {
    stageN(xs, A.sT, 512, b0P, tid); __syncthreads();
    if (tid < 512) {
      float acc[16] = {0,0,0,0,0,0,0,0,0,0,0,0,0,0,0,0};
      gemm16<64>(A.cU1, colbaseP, kqP, cgP, bgP, xs, acc);
      pstore(part, kqP, cgP, bgP, acc);
    }
    __syncthreads();
    epi_plain<1>(nullptr, A.ggate, colbaseP, b0P, tid, part);
  }
  gbar();
  cond_nl(A.ggate, A.cb1, A.sT + (size_t)512 * Bn, A.h1cT, bid, tid);
  gbar();
  // ---- pre2: conductor L2 gates ----
  {
    stageN(xs, A.h1cT, 512, b0P, tid);
    stageN(xs + 8192, A.sT + (size_t)1024 * Bn, 512, b0P, tid);
    __syncthreads();
    if (tid < 512) {
      float acc[16] = {0,0,0,0,0,0,0,0,0,0,0,0,0,0,0,0};
      gemm16<64>(A.cW2, colbaseP, kqP, cgP, bgP, xs, acc);
      gemm16<64>(A.cU2, colbaseP, kqP, cgP, bgP, xs + 8192, acc);
      pstore(part, kqP, cgP, bgP, acc);
    }
    __syncthreads();
    epi_plain<1>(nullptr, A.ggate, colbaseP, b0P, tid, part);
  }
  gbar();
  cond_nl(A.ggate, A.cb2, A.sT + (size_t)1536 * Bn, A.ceT, bid, tid);
  gbar();
  // ---- pre3: sdT, beffP ----
  {
    stageN(xs, A.ceT, 512, b0P, tid); __syncthreads();
    if (tid < 512) {
      float acc[16] = {0,0,0,0,0,0,0,0,0,0,0,0,0,0,0,0};
      gemm16<64>(A.Wcd, colbaseP, kqP, cgP, bgP, xs, acc);
      pstore(part, kqP, cgP, bgP, acc);
    }
    __syncthreads();
    epi_plain<0>(A.bcd, A.sdT, colbaseP, b0P, tid, part);
    __syncthreads();
    if (tid < 512) {
      float acc[16] = {0,0,0,0,0,0,0,0,0,0,0,0,0,0,0,0};
      gemm16<64>(A.WEp, colbaseP, kqP, cgP, bgP, xs, acc);
      pstore(part, kqP, cgP, bgP, acc);
    }
    __syncthreads();
    epi_plain<1>(A.db1P, A.beffP, colbaseP, b0P, tid, part);
  }
  gbar();
  // ---- P4: WB pack (16j x 32ks x 8nt; overwrites WEp) + dh packs ----
  {
    const int i0 = bid * NTHR + tid;
    for (int i = i0; i < 1048576; i += NBLK * NTHR) {
      int col = i & 2047, kp = i >> 11, k = kp * 2;
      float w0, w1;
      if (k < 512) { w0 = A.dW2[(size_t)k * NGn + col];         w1 = A.dW2[(size_t)(k + 1) * NGn + col]; }
      else         { w0 = A.dU2[(size_t)(k - 512) * NGn + col]; w1 = A.dU2[(size_t)(k - 511) * NGn + col]; }
      unsigned short h0, l0, h1, l1; split2(w0, h0, l0); split2(w1, h1, l1);
      int g = col >> 9, hid = col & 511;
      int jb = hid >> 5;
      int jcol = (hid & 31) * 4 + g;
      int nt = jcol >> 4, n = jcol & 15;
      int ks = k >> 5, kr = k & 31, lh = kr >> 3, q = (kr >> 1) & 3;
      int idx = ((jb * 32 + ks) * 8 + nt) * 256 + (lh * 16 + n) * 4 + q;
      astoreU(A.WBh + idx, (uint)h0 | ((uint)h1 << 16));
      astoreU(A.WBl + idx, (uint)l0 | ((uint)l1 << 16));
    }
    if (i0 < 512 * Bn) {
      int hid = i0 >> 7, b = i0 & 127;
      astoreU(A.dh1pk + ((size_t)((hid >> 3) * 128 + b)) * 8 + (hid & 7),
              packsplit(aloadF(A.sdT + (size_t)hid * Bn + b)));
      astoreU(A.dh2pk + ((size_t)((hid >> 3) * 128 + b)) * 8 + (hid & 7),
              packsplit(aloadF(A.sdT + (size_t)(1024 + hid) * Bn + b)));
    }
  }
}

// ---------------- main kernel (256 blocks = 16 pods x 16 blocks) ----------------
// frag maps (rounds 5-13 verified): A(x): m=lane&15, k=(lane>>4)*8+e.
// B(w): n=lane&15, k=(lane>>4)*8+e. D: n=lane&15, m=(lane>>4)*4+reg.
// pod = 8 batches -> m lanes 8..15 are junk (in-bounds reads, results discarded).
__device__ __forceinline__ void unpack64(const u64* d, FR& xh, FR& xl) {
  #pragma unroll
  for (int q = 0; q < 4; q++) {
    uint lo = (uint)d[q], hi = (uint)(d[q] >> 32);
    xh.u[q] = (lo & 0xffffu) | (hi << 16);
    xl.u[q] = (lo >> 16) | (hi & 0xffff0000u);
  }
}
__device__ __forceinline__ void unpackL9(const uint* __restrict__ p, FR& xh, FR& xl) {
  uint w[8];
  #pragma unroll
  for (int e = 0; e < 8; e++) w[e] = p[e * 9];
  xh.u[0] = (w[0] & 0xffffu) | (w[1] << 16); xl.u[0] = (w[0] >> 16) | (w[1] & 0xffff0000u);
  xh.u[1] = (w[2] & 0xffffu) | (w[3] << 16); xl.u[1] = (w[2] >> 16) | (w[3] & 0xffff0000u);
  xh.u[2] = (w[4] & 0xffffu) | (w[5] << 16); xl.u[2] = (w[4] >> 16) | (w[5] & 0xffff0000u);
  xh.u[3] = (w[6] & 0xffffu) | (w[7] << 16); xl.u[3] = (w[6] >> 16) | (w[7] & 0xffff0000u);
}

#define MFMA3(ACC, XH, XL, WH, WL)                                            \
  ACC = __builtin_amdgcn_mfma_f32_16x16x32_bf16(XH.s, WH.s, ACC, 0, 0, 0);    \
  ACC = __builtin_amdgcn_mfma_f32_16x16x32_bf16(XL.s, WH.s, ACC, 0, 0, 0);    \
  ACC = __builtin_amdgcn_mfma_f32_16x16x32_bf16(XH.s, WL.s, ACC, 0, 0, 0);

// one ks across all 8 nt tiles
__device__ __forceinline__ void doKS8(const uint* WH, const uint* WL, int ks, int lane,
                                      const FR& xh, const FR& xl, f32x4 acc[8]) {
  #pragma unroll
  for (int nt = 0; nt < 8; nt++) {
    FR wh, wl;
    *(uint4*)wh.u = *(const uint4*)(WH + (ks * 8 + nt) * 256 + lane * 4);
    *(uint4*)wl.u = *(const uint4*)(WL + (ks * 8 + nt) * 256 + lane * 4);
    MFMA3(acc[nt], xh, xl, wh, wl)
  }
}

__global__ void __launch_bounds__(NTHR, 1)
hd_main(KA A) {
  __shared__ float buf[21632];
  float* plog = buf;                 // 128 slots x 4 r x 33 = 16896
  uint*  NT   = (uint*)(buf + 16896);// 192 rows x 9 = 1728 (+pad 32)
  float* gbuf = buf + 18656;         // 128 cols x 8 b = 1024
  float* cst  = buf + 19680;         // c1[256] | c2[256]
  float* h2s  = buf + 20192;         // 32 x 8 = 256
  float* beffL= buf + 20448;         // 1024
  float* db2L = buf + 21472;         // 128

  const int bid = blockIdx.x, tid = threadIdx.x;
  const int wid = tid >> 6, lane = tid & 63;
  const int m = lane & 15, kh = lane >> 4;
  const int j = bid & 15, pod = bid >> 4;
  const int b0 = pod * 8;

  unsigned tgt = aloadU(&pod_slot[(pod * 16 + j) * 32]) + 1;

  // ---- block init ----
  {
    int cl = tid >> 3, bl = tid & 7;          // 128 cols x 8 b
    beffL[tid] = aloadF(A.beffP + (size_t)(j * 128 + cl) * Bn + b0 + bl);
  }
  if (tid < 128) db2L[tid] = A.db2P[j * 128 + tid];
  for (int i = tid; i < 1760; i += NTHR) NT[i] = 0u;   // note(0)=0 + pads
  __syncthreads();

  int* accI = A.accI + pod * 1536;

  for (int t = 0; t <= TTn; t++) {
    const int par = t & 1;
    const bool rst = (t & 15) == 0;
    const bool last = (t == TTn);

    // ==== top-of-step prefetch ====
    int ai0 = 0, ai1 = 0, ai2 = 0;
    if (t > 0 && wid < 8) {
      const int* ai = accI + ((par ^ 1) * ACC_PAR) + wid * 192 + lane;
      ai0 = aloadI(ai); ai1 = aloadI(ai + 64); ai2 = aloadI(ai + 128);
    }
    u64 xa[8]; u64 xb[8];
    if (!last) {
      const uint* hsrcA = rst ? A.dh1pk : (A.h1pk + (par ^ 1) * HPAR);
      if (wid >= 3 && wid < 6) {
        #pragma unroll
        for (int i = 0; i < 2; i++) {
          const u64* p = (const u64*)hsrcA
                       + ((size_t)(((wid * 2 - 6 + i) * 4 + kh) * 128 + b0 + m)) * 4;
          #pragma unroll
          for (int q = 0; q < 4; q++) xa[i * 4 + q] = aload64(p + q);
        }
      } else if (wid >= 6) {
        const u64* p = (const u64*)hsrcA + ((size_t)((wid * 4 + kh) * 128 + b0 + m)) * 4;
        #pragma unroll
        for (int q = 0; q < 4; q++) xa[q] = aload64(p + q);
      }
      if (wid >= 8) {
        const uint* s2 = rst ? A.dh2pk : (A.h2pk + (par ^ 1) * HPAR);
        #pragma unroll
        for (int i = 0; i < 2; i++) {
          const int ks = wid * 2 + i;           // 16..31
          const u64* p = (const u64*)s2
                       + ((size_t)(((ks & 15) * 4 + kh) * 128 + b0 + m)) * 4;
          #pragma unroll
          for (int q = 0; q < 4; q++) xb[i * 4 + q] = aload64(p + q);
        }
      }
    }

    // ==== softmax front (t>0): waves 0..7 = batches 0..7 ====
    if (t > 0 && wid < 8) {
      float lg[3], pv[3];
      lg[0] = (lane < DOn)     ? (float)ai0 * (1.0f/1048576.0f) + A.bp[lane]     : -1e30f;
      lg[1] = (lane+64 < DOn)  ? (float)ai1 * (1.0f/1048576.0f) + A.bp[lane+64]  : -1e30f;
      lg[2] = (lane+128 < DOn) ? (float)ai2 * (1.0f/1048576.0f) + A.bp[lane+128] : -1e30f;
      float mx = fmaxf(fmaxf(lg[0], lg[1]), lg[2]);
      #pragma unroll
      for (int d = 1; d < 64; d <<= 1) mx = fmaxf(mx, __shfl_xor(mx, d));
      float sum = 0.f;
      #pragma unroll
      for (int rep = 0; rep < 3; rep++) {
        int o = lane + rep * 64;
        pv[rep] = (o < DOn) ? __expf(lg[rep] - mx) : 0.f;
        sum += pv[rep];
      }
      #pragma unroll
      for (int d = 1; d < 64; d <<= 1) sum += __shfl_xor(sum, d);
      const float inv = 1.0f / sum;
      #pragma unroll
      for (int rep = 0; rep < 3; rep++) {
        int o = lane + rep * 64;
        float p = pv[rep] * inv;
        NT[o * 9 + wid] = (o < DOn) ? packsplit(p) : 0u;
        if (j == wid && o < DOn)
          A.out[((size_t)(b0 + wid) * TTn + (t - 1)) * DOn + o] = p;
      }
    }
    __syncthreads();
    if (last) break;

    // ==== decoder L1: wave = k-slice, 8 nt tiles ====
    {
      const uint* WH = A.WAh + (size_t)j * 45056;
      const uint* WL = A.WAl + (size_t)j * 45056;
      f32x4 acc[8] = {{0,0,0,0},{0,0,0,0},{0,0,0,0},{0,0,0,0},
                      {0,0,0,0},{0,0,0,0},{0,0,0,0},{0,0,0,0}};
      if (wid < 3) {
        #pragma unroll
        for (int i = 0; i < 2; i++) {
          const int ks = wid * 2 + i;
          FR xh, xl; unpackL9(NT + (ks * 32 + kh * 8) * 9 + m, xh, xl);
          doKS8(WH, WL, ks, lane, xh, xl, acc);
        }
      } else if (wid < 6) {
        FR xh, xl;
        unpack64(&xa[0], xh, xl); doKS8(WH, WL, wid * 2, lane, xh, xl, acc);
        unpack64(&xa[4], xh, xl); doKS8(WH, WL, wid * 2 + 1, lane, xh, xl, acc);
      } else {
        FR xh, xl; unpack64(&xa[0], xh, xl);
        doKS8(WH, WL, 12 + (wid - 6), lane, xh, xl, acc);
      }
      if (lane < 32) {                       // lanes 0..31 hold valid m-rows 0..7
        #pragma unroll
        for (int nt = 0; nt < 8; nt++)
          #pragma unroll
          for (int r = 0; r < 4; r++)
            plog[((wid * 8 + nt) * 4 + r) * 33 + lane] = acc[nt][r];
      }
    }
    __syncthreads();
    // reduce 16 k-slices: thread = (col 0..127, b 0..7)
    {
      const int cl = tid >> 3, bl = tid & 7;
      float s = 0.f;
      #pragma unroll
      for (int k2 = 0; k2 < 16; k2++)
        s += plog[((k2 * 8 + (cl >> 4)) * 4 + (bl & 3)) * 33 + (bl >> 2) * 16 + (cl & 15)];
      gbuf[cl * 8 + bl] = s + beffL[cl * 8 + bl];
    }
    __syncthreads();
    if (tid < 256) {                         // epilogue L1: (hid_local 0..31, b 0..7)
      const int hl = tid >> 3, bl = tid & 7;
      float gi = gbuf[(hl*4+0)*8+bl], gf = gbuf[(hl*4+1)*8+bl];
      float gg = gbuf[(hl*4+2)*8+bl], go = gbuf[(hl*4+3)*8+bl];
      const int hid = j * 32 + hl;
      float cp = rst ? aloadF(A.sdT + (size_t)(512 + hid) * Bn + b0 + bl) : cst[tid];
      float cc = sigm(gf) * cp + sigm(gi) * tanhf(gg);
      cst[tid] = cc;
      astoreU(A.h1pk + par * HPAR + ((size_t)((hid >> 3) * 128 + b0 + bl)) * 8 + (hid & 7),
              packsplit(sigm(go) * tanhf(cc)));
    }
    pbarS(pod, j, tgt);

    // ==== decoder L2 ====
    if (wid < 8) {
      const uint* s1 = A.h1pk + par * HPAR;
      #pragma unroll
      for (int i = 0; i < 2; i++) {
        const int ks = wid * 2 + i;
        const u64* p = (const u64*)s1 + ((size_t)((ks * 4 + kh) * 128 + b0 + m)) * 4;
        #pragma unroll
        for (int q = 0; q < 4; q++) xb[i * 4 + q] = aload64(p + q);
      }
    }
    {
      const uint* WH = A.WBh + (size_t)j * 65536;
      const uint* WL = A.WBl + (size_t)j * 65536;
      f32x4 acc[8] = {{0,0,0,0},{0,0,0,0},{0,0,0,0},{0,0,0,0},
                      {0,0,0,0},{0,0,0,0},{0,0,0,0},{0,0,0,0}};
      FR xh, xl;
      unpack64(&xb[0], xh, xl); doKS8(WH, WL, wid * 2, lane, xh, xl, acc);
      unpack64(&xb[4], xh, xl); doKS8(WH, WL, wid * 2 + 1, lane, xh, xl, acc);
      if (lane < 32) {
        #pragma unroll
        for (int nt = 0; nt < 8; nt++)
          #pragma unroll
          for (int r = 0; r < 4; r++)
            plog[((wid * 8 + nt) * 4 + r) * 33 + lane] = acc[nt][r];
      }
    }
    __syncthreads();
    {
      const int cl = tid >> 3, bl = tid & 7;
      float s = 0.f;
      #pragma unroll
      for (int k2 = 0; k2 < 16; k2++)
        s += plog[((k2 * 8 + (cl >> 4)) * 4 + (bl & 3)) * 33 + (bl >> 2) * 16 + (cl & 15)];
      gbuf[cl * 8 + bl] = s + db2L[cl];
    }
    __syncthreads();
    if (tid < 256) {                         // epilogue L2
      const int hl = tid >> 3, bl = tid & 7;
      float gi = gbuf[(hl*4+0)*8+bl], gf = gbuf[(hl*4+1)*8+bl];
      float gg = gbuf[(hl*4+2)*8+bl], go = gbuf[(hl*4+3)*8+bl];
      const int hid = j * 32 + hl;
      float cp = rst ? aloadF(A.sdT + (size_t)(1536 + hid) * Bn + b0 + bl) : cst[256 + tid];
      float cc = sigm(gf) * cp + sigm(gi) * tanhf(gg);
      cst[256 + tid] = cc;
      float h2v = sigm(go) * tanhf(cc);
      h2s[hl * 8 + bl] = h2v;
      astoreU(A.h2pk + par * HPAR + ((size_t)((hid >> 3) * 128 + b0 + bl)) * 8 + (hid & 7),
              packsplit(h2v));
    }
    __syncthreads();
    // partial projection logits over this block's 32-hid slice -> fixed-point atomics
    {
      const int o = tid & 255, q = tid >> 8;       // q: 4 groups x 2 batches
      if (o < DOn) {
        float s0 = 0.f, s1 = 0.f;
        #pragma unroll
        for (int h = 0; h < 32; h++) {
          const float w = A.Wp[(size_t)(j * 32 + h) * DOn + o];
          s0 = fmaf(h2s[h * 8 + q * 2 + 0], w, s0);
          s1 = fmaf(h2s[h * 8 + q * 2 + 1], w, s1);
        }
        __hip_atomic_fetch_add(accI + par * ACC_PAR + (q * 2 + 0) * 192 + o,
                               __float2int_rn(s0 * 1048576.0f),
                               __ATOMIC_RELAXED, __HIP_MEMORY_SCOPE_AGENT);
        __hip_atomic_fetch_add(accI + par * ACC_PAR + (q * 2 + 1) * 192 + o,
                               __float2int_rn(s1 * 1048576.0f),
                               __ATOMIC_RELAXED, __HIP_MEMORY_SCOPE_AGENT);
      }
      if (tid < 96)
        astoreU((uint*)(accI + (par ^ 1) * ACC_PAR + j * 96 + tid), 0u);
    }
    pbarS(pod, j, tgt);
  }
}

extern "C" void kernel_launch(void* const* d_in, const int* in_sizes, int n_in,
                              void* d_out, int out_size, void* d_ws, size_t ws_size,
                              hipStream_t stream) {
  (void)in_sizes; (void)n_in; (void)out_size; (void)ws_size;
  KA a;
  a.z   = (const float*)d_in[0];
  a.Wz  = (const float*)d_in[3];  a.bz  = (const float*)d_in[4];
  // d_in[5] = cond_W1 unused (conductor input x0 == 0)
  a.cU1 = (const float*)d_in[6];  a.cb1 = (const float*)d_in[7];
  a.cW2 = (const float*)d_in[8];  a.cU2 = (const float*)d_in[9];  a.cb2 = (const float*)d_in[10];
  a.Wcd = (const float*)d_in[11]; a.bcd = (const float*)d_in[12];
  a.dW1 = (const float*)d_in[13]; a.dU1 = (const float*)d_in[14]; a.db1 = (const float*)d_in[15];
  a.dW2 = (const float*)d_in[16]; a.dU2 = (const float*)d_in[17]; a.db2 = (const float*)d_in[18];
  a.Wp  = (const float*)d_in[19]; a.bp  = (const float*)d_in[20];

  float* ws = (float*)d_ws;
  size_t off = 0;
  a.zT    = ws + off; off += (size_t)512  * Bn;
  a.sT    = ws + off; off += (size_t)NGn  * Bn;
  a.ggate = ws + off; off += (size_t)NGn  * Bn;
  a.h1cT  = ws + off; off += (size_t)512  * Bn;
  a.ceT   = ws + off; off += (size_t)512  * Bn;
  a.sdT   = ws + off; off += (size_t)NGn  * Bn;       // dh1|dc1|dh2|dc2
  a.beffP = ws + off; off += (size_t)NGn  * Bn;       // [cp][b]
  a.db1P  = ws + off; off += (size_t)NGn;
  a.db2P  = ws + off; off += (size_t)NGn;
  a.WEp   = ws + off; off += (size_t)512 * NGn;       // aliased by WBh in P4
  a.WBh   = (uint*)a.WEp;
  a.WBl   = (uint*)(ws + off); off += (size_t)1048576;
  a.WAh   = (uint*)(ws + off); off += (size_t)720896;
  a.WAl   = (uint*)(ws + off); off += (size_t)720896;
  a.h1pk  = (uint*)(ws + off); off += (size_t)2 * HPAR;
  a.h2pk  = (uint*)(ws + off); off += (size_t)2 * HPAR;
  a.dh1pk = (uint*)(ws + off); off += (size_t)HPAR;
  a.dh2pk = (uint*)(ws + off); off += (size_t)HPAR;
  a.accI  = (int*)(ws + off);  off += (size_t)2 * ACC_PAR;
  a.out   = (float*)d_out;

  hd_prep<<<dim3(NBLK), dim3(NTHR), 0, stream>>>(a);
  hd_main<<<dim3(NBLK), dim3(NTHR), 0, stream>>>(a);
}